// Round 4
// baseline (124.395 us; speedup 1.0000x reference)
//
#include <hip/hip_runtime.h>
#include <hip/hip_bf16.h>

// PairwiseScore: B=2, N=256, E=512, H=150 (padded to 160)
// out[b,i,j] = (m[b,i] + m[b,j] + MLP3(g_i, g_j)) / 3
//
// Fold: hij + hj = sum_e (g_i[e]*W1c[e,h] + W1b[e,h]) * g_j[e]
// R4 structure (one block per (b,i), 1024 thr = 16 waves = 2 hg x 8 jg):
//  - wave owns 5 h-tiles x 2 j-tiles -> acc = 40 regs (was 80) -> 4 waves/SIMD
//  - h1 exchanged through LDS [j][h] (stride 168 shorts, ~conflict-free),
//    phase-2 B-frags are plain ds_read_b128 (shfl transform removed)
//  - W2^T A-frags read directly from L2 with register ping-pong (no staging)
//  - B-frags (g_j) software-pipelined via register ping-pong

typedef __attribute__((ext_vector_type(4))) float f32x4;
typedef __attribute__((ext_vector_type(4))) unsigned int u32x4;
typedef __attribute__((ext_vector_type(2))) unsigned int u32x2;
typedef __attribute__((ext_vector_type(8))) short short8;

#define NB 2
#define NN 256
#define NE 512
#define NH 150
#define HP 160      // padded H
#define NKT 16      // NE/32 k-tiles for GEMM1
#define NHT 10      // HP/16 h-tiles
#define NS 5        // HP/32 k-steps for GEMM2
#define H1S 168     // h1 LDS row stride in shorts (84 words; gcd(84%32,32)=4 -> ~2-way)

// ---------- helpers ----------
__device__ __forceinline__ unsigned pk_bf16(float a, float b) {
  unsigned ua = __builtin_bit_cast(unsigned, a);
  unsigned ub = __builtin_bit_cast(unsigned, b);
  ua += 0x7fffu + ((ua >> 16) & 1u);
  ub += 0x7fffu + ((ub >> 16) & 1u);
  return (ua >> 16) | (ub & 0xffff0000u);
}
__device__ __forceinline__ float bf_lo(unsigned u) { return __builtin_bit_cast(float, u << 16); }
__device__ __forceinline__ float bf_hi(unsigned u) { return __builtin_bit_cast(float, u & 0xffff0000u); }

// ---------- prep: grid 309 x 256 (unchanged from R3) ----------
__global__ __launch_bounds__(256) void prep_pack(
    const float* __restrict__ g, const float* __restrict__ W1,
    const float* __restrict__ W2,
    unsigned short* __restrict__ g_bf16, unsigned short* __restrict__ WaF,
    unsigned short* __restrict__ WbF, unsigned short* __restrict__ WcF,
    unsigned short* __restrict__ W2TF)
{
  int bid = blockIdx.x, tid = threadIdx.x;
  if (bid < 256) {
    int t = bid * 256 + tid;
    f32x4 v = ((const f32x4*)g)[t];
    u32x2 o; o[0] = pk_bf16(v[0], v[1]); o[1] = pk_bf16(v[2], v[3]);
    ((u32x2*)g_bf16)[t] = o;
  } else if (bid < 296) {
    int row = (bid - 256) * 256 + tid;       // 0..10239 = 16kt*10ht*64lane
    int kt = row / 640; int rem = row - kt * 640;
    int l = rem & 63; int chh = rem >> 6;
    int e = kt * 32 + (l >> 4) * 8;
    int h = chh * 16 + (l & 15);
    u32x4 oa, ob, oc;
#pragma unroll
    for (int q = 0; q < 4; ++q) {
      int e0 = e + 2 * q, e1 = e0 + 1;
      float va0 = 0.f, va1 = 0.f, vb0 = 0.f, vb1 = 0.f, vc0 = 0.f, vc1 = 0.f;
      if (h < NH) {
        va0 = W1[(size_t)e0 * NH + h];          va1 = W1[(size_t)e1 * NH + h];
        vb0 = W1[(size_t)(512 + e0) * NH + h];  vb1 = W1[(size_t)(512 + e1) * NH + h];
        vc0 = W1[(size_t)(1024 + e0) * NH + h]; vc1 = W1[(size_t)(1024 + e1) * NH + h];
      }
      oa[q] = pk_bf16(va0, va1);
      ob[q] = pk_bf16(vb0, vb1);
      oc[q] = pk_bf16(vc0, vc1);
    }
    ((u32x4*)WaF)[row] = oa;
    ((u32x4*)WbF)[row] = ob;
    ((u32x4*)WcF)[row] = oc;
  } else {
    int row = (bid - 296) * 256 + tid;       // < 3200 = 5s*10ht*64lane
    if (row < 3200) {
      int s = row / 640; int rem = row - s * 640;
      int l = rem & 63; int chh = rem >> 6;
      int k = s * 32 + (l >> 4) * 8;
      int hp = chh * 16 + (l & 15);
      u32x4 o;
#pragma unroll
      for (int q = 0; q < 4; ++q) {
        int k0 = k + 2 * q, k1 = k0 + 1;
        float v0 = (k0 < NH && hp < NH) ? W2[(size_t)k0 * NH + hp] : 0.f;
        float v1 = (k1 < NH && hp < NH) ? W2[(size_t)k1 * NH + hp] : 0.f;
        o[q] = pk_bf16(v0, v1);
      }
      ((u32x4*)W2TF)[row] = o;
    }
  }
}

// ---------- main fused kernel: 1024 threads, one block per (b,i) ----------
__global__ __launch_bounds__(1024) void pair_main(
    const float* __restrict__ mention, const float* __restrict__ b1,
    const float* __restrict__ b2, const float* __restrict__ W3,
    const float* __restrict__ b3,
    const unsigned short* __restrict__ g_bf16,
    const unsigned short* __restrict__ WaF,
    const unsigned short* __restrict__ WbF, const unsigned short* __restrict__ WcF,
    const unsigned short* __restrict__ W2TF,
    float* __restrict__ out)
{
  // stage (A~ mega-tile, 80 KB) and h1 (86 KB) share this buffer
  __shared__ alignas(16) unsigned short h1s[NN * H1S];  // 86016 B
  __shared__ unsigned int gi_lds[NE / 2];               // g_i as bf16 (1 KB)
  __shared__ alignas(16) float bias1[HP];               // b1 + hi (via mini-MFMA)
  __shared__ alignas(16) float bias2[HP];
  __shared__ alignas(16) float w3s[HP];
  __shared__ float ps[NN];                              // cross-hg partial scores

  const int tid = threadIdx.x;
  const int bi = blockIdx.x;
  const int b = bi >> 8, i = bi & 255;
  const int lane = tid & 63, wave = tid >> 6;           // 16 waves
  const int c16 = lane & 15, quad = lane >> 4;
  const int hg = wave & 1, jg = wave >> 1;              // 2 h-groups x 8 j-groups

  // ---- phase 0: per-block constants into LDS ----
  {
    if (tid < 64) {
      const u32x4* grow = (const u32x4*)(g_bf16 + (size_t)(b * NN + i) * NE);
      ((u32x4*)gi_lds)[tid] = grow[tid];
    }
    if (tid >= 64 && tid < 64 + HP) {
      int h = tid - 64;
      bias1[h] = (h < NH) ? b1[h] : 0.f;
      bias2[h] = (h < NH) ? b2[h] : 0.f;
      w3s[h]   = (h < NH) ? W3[h] : 0.f;
    }
  }
  __syncthreads();   // barrier A

  // ---- builder: A~[h,e] = g_i[e]*W1c[e,h] + W1b[e,h], 5 rows/thread ----
  auto build_mega = [&](int mega) {
#pragma unroll
    for (int r = 0; r < 5; ++r) {
      int v = tid + r * 1024;                // 0..5119
      int ktl = v / 640; int rem = v - ktl * 640;
      int l = rem & 63;
      int ktg = mega * 8 + ktl;
      int gidx = ktg * 640 + (rem >> 6) * 64 + l;
      u32x4 wb = ((const u32x4*)WbF)[gidx];
      u32x4 wc = ((const u32x4*)WcF)[gidx];
      u32x4 gi = ((const u32x4*)gi_lds)[ktg * 4 + (l >> 4)];
      u32x4 o;
#pragma unroll
      for (int q = 0; q < 4; ++q) {
        float lo = bf_lo(gi[q]) * bf_lo(wc[q]) + bf_lo(wb[q]);
        float hi = bf_hi(gi[q]) * bf_hi(wc[q]) + bf_hi(wb[q]);
        o[q] = pk_bf16(lo, hi);
      }
      ((u32x4*)h1s)[v] = o;
    }
  };

  // ---- mega 0 build; waves 0-9 also compute hi via mini-MFMA (broadcast B) ----
  build_mega(0);
  if (wave < NHT) {
    f32x4 ah = {};
#pragma unroll
    for (int kt = 0; kt < NKT; ++kt) {
      short8 bbc = __builtin_bit_cast(short8, ((const u32x4*)gi_lds)[kt * 4 + quad]);
      short8 a0 = __builtin_bit_cast(short8,
          ((const u32x4*)WaF)[(kt * NHT + wave) * 64 + lane]);
      ah = __builtin_amdgcn_mfma_f32_16x16x32_bf16(a0, bbc, ah, 0, 0, 0);
    }
    if (c16 == 0) {
#pragma unroll
      for (int r = 0; r < 4; ++r)
        bias1[wave * 16 + quad * 4 + r] += ah[r];
    }
  }
  __syncthreads();   // barrier B

  // ---- phase 1: D1[h][j] = A~ * g_j, 5 ht x 2 jt per wave ----
  f32x4 acc1[5][2] = {};
  const u32x4* gB = (const u32x4*)g_bf16;
  const int jbase = jg * 32 + c16;
  const size_t gidx0 = (size_t)(b * NN + jbase) * 64 + quad;   // u32x4 units

#pragma unroll 1
  for (int mega = 0; mega < 2; ++mega) {
    u32x4 nb0 = gB[gidx0 + (size_t)(mega * 8) * 4];
    u32x4 nb1 = gB[gidx0 + 16 * 64 + (size_t)(mega * 8) * 4];
#pragma unroll 1
    for (int ktl = 0; ktl < 8; ++ktl) {
      u32x4 cb0 = nb0, cb1 = nb1;
      if (ktl < 7) {
        int ktg = mega * 8 + ktl + 1;
        nb0 = gB[gidx0 + (size_t)ktg * 4];
        nb1 = gB[gidx0 + 16 * 64 + (size_t)ktg * 4];
      }
      short8 bf0 = __builtin_bit_cast(short8, cb0);
      short8 bf1 = __builtin_bit_cast(short8, cb1);
      const u32x4* As = (const u32x4*)h1s + ktl * (NHT * 64);
#pragma unroll
      for (int ht = 0; ht < 5; ++ht) {
        short8 af = __builtin_bit_cast(short8, As[(hg * 5 + ht) * 64 + lane]);
        acc1[ht][0] = __builtin_amdgcn_mfma_f32_16x16x32_bf16(af, bf0, acc1[ht][0], 0, 0, 0);
        acc1[ht][1] = __builtin_amdgcn_mfma_f32_16x16x32_bf16(af, bf1, acc1[ht][1], 0, 0, 0);
      }
    }
    if (mega == 0) {
      __syncthreads();   // barrier C: mega-0 reads done
      build_mega(1);
      __syncthreads();   // barrier D: mega-1 A~ ready
    }
  }
  __syncthreads();       // barrier E: stage reads done; buffer becomes h1

  // ---- epilogue 1: h1 = relu(D1 + hi + b1) -> bf16 into LDS [j][h] ----
#pragma unroll
  for (int ht = 0; ht < 5; ++ht) {
    int HT = hg * 5 + ht;
    f32x4 bv = *(const f32x4*)(bias1 + HT * 16 + quad * 4);
#pragma unroll
    for (int jt = 0; jt < 2; ++jt) {
      f32x4 v = acc1[ht][jt];
      float r0 = fmaxf(v[0] + bv[0], 0.f);
      float r1 = fmaxf(v[1] + bv[1], 0.f);
      float r2 = fmaxf(v[2] + bv[2], 0.f);
      float r3 = fmaxf(v[3] + bv[3], 0.f);
      int j = jg * 32 + jt * 16 + c16;
      int addr = j * H1S + HT * 16 + quad * 4;        // shorts; %4==0 -> 8B aligned
      u32x2 pr; pr[0] = pk_bf16(r0, r1); pr[1] = pk_bf16(r2, r3);
      *(u32x2*)(h1s + addr) = pr;
    }
  }
  __syncthreads();       // barrier F: h1 complete

  // ---- phase 2: D2[h'][j] = W2^T * h1 ; A from L2 (ping-pong), B from LDS ----
  f32x4 acc2[5][2] = {};
  u32x4 wf[2][5];
#pragma unroll
  for (int ht = 0; ht < 5; ++ht)
    wf[0][ht] = ((const u32x4*)W2TF)[(0 * NHT + hg * 5 + ht) * 64 + lane];

#pragma unroll
  for (int s = 0; s < NS; ++s) {
    if (s + 1 < NS) {
#pragma unroll
      for (int ht = 0; ht < 5; ++ht)
        wf[(s + 1) & 1][ht] =
            ((const u32x4*)W2TF)[((s + 1) * NHT + hg * 5 + ht) * 64 + lane];
    }
    short8 b2f[2];
#pragma unroll
    for (int jt = 0; jt < 2; ++jt) {
      int j = jg * 32 + jt * 16 + c16;
      int addr = j * H1S + s * 32 + quad * 8;         // shorts; 16B aligned
      b2f[jt] = *(const short8*)(h1s + addr);
    }
#pragma unroll
    for (int ht = 0; ht < 5; ++ht) {
      short8 af = __builtin_bit_cast(short8, wf[s & 1][ht]);
      acc2[ht][0] = __builtin_amdgcn_mfma_f32_16x16x32_bf16(af, b2f[0], acc2[ht][0], 0, 0, 0);
      acc2[ht][1] = __builtin_amdgcn_mfma_f32_16x16x32_bf16(af, b2f[1], acc2[ht][1], 0, 0, 0);
    }
  }

  // ---- epilogue 2 + GEMM3: partial score over own h' range ----
  float part0 = 0.f, part1 = 0.f;
#pragma unroll
  for (int ht = 0; ht < 5; ++ht) {
    int HT = hg * 5 + ht;
    f32x4 bv = *(const f32x4*)(bias2 + HT * 16 + quad * 4);
    f32x4 wv = *(const f32x4*)(w3s + HT * 16 + quad * 4);
    f32x4 v0 = acc2[ht][0], v1 = acc2[ht][1];
#pragma unroll
    for (int r = 0; r < 4; ++r) {
      part0 += fmaxf(v0[r] + bv[r], 0.f) * wv[r];
      part1 += fmaxf(v1[r] + bv[r], 0.f) * wv[r];
    }
  }
  part0 += __shfl_xor(part0, 16); part0 += __shfl_xor(part0, 32);
  part1 += __shfl_xor(part1, 16); part1 += __shfl_xor(part1, 32);

  // ---- cross-hg combine via LDS, hg1 writes out ----
  if (hg == 0) {
    if (quad == 0) ps[jg * 32 + c16] = part0;
    if (quad == 1) ps[jg * 32 + 16 + c16] = part1;
  }
  __syncthreads();       // barrier G

  if (hg == 1 && quad < 2) {
    int j = jg * 32 + quad * 16 + c16;
    float sc = (quad == 0) ? part0 : part1;
    float mi = mention[b * NN + i];
    float mj = mention[b * NN + j];
    out[((size_t)(b * NN + i)) * NN + j] =
        (mi + mj + ps[j] + sc + b3[0]) * (1.f / 3.f);
  }
}

// ---------- launch ----------
extern "C" void kernel_launch(void* const* d_in, const int* in_sizes, int n_in,
                              void* d_out, int out_size, void* d_ws, size_t ws_size,
                              hipStream_t stream) {
  const float* g  = (const float*)d_in[0];
  const float* m  = (const float*)d_in[1];
  const float* W1 = (const float*)d_in[2];
  const float* b1 = (const float*)d_in[3];
  const float* W2 = (const float*)d_in[4];
  const float* b2 = (const float*)d_in[5];
  const float* W3 = (const float*)d_in[6];
  const float* b3 = (const float*)d_in[7];
  float* out = (float*)d_out;

  char* ws = (char*)d_ws;
  unsigned short* g_bf16 = (unsigned short*)(ws);              // 524288 B
  unsigned short* WaF    = (unsigned short*)(ws + 524288);     // 163840 B
  unsigned short* WbF    = (unsigned short*)(ws + 688128);     // 163840 B
  unsigned short* WcF    = (unsigned short*)(ws + 851968);     // 163840 B
  unsigned short* W2TF   = (unsigned short*)(ws + 1015808);    //  51200 B (total ~1.02 MB)

  prep_pack<<<309, 256, 0, stream>>>(g, W1, W2, g_bf16, WaF, WbF, WcF, W2TF);
  pair_main<<<512, 1024, 0, stream>>>(m, b1, b2, W3, b3, g_bf16, WaF, WbF, WcF, W2TF, out);
}